// Round 1
// baseline (144.289 us; speedup 1.0000x reference)
//
#include <hip/hip_runtime.h>
#include <math.h>

// Problem constants (fixed by setup_inputs shapes).
constexpr int Bc  = 8;
constexpr int Tc  = 4096;
constexpr int HLc = 8;
constexpr int Dc  = 128;
constexpr int Sc  = 4096;
constexpr int TBc = 64;   // Tb = T / bs
constexpr int BSc = 64;   // sparse_block_size

// Output offsets (float elements) in concatenated d_out, in return order.
constexpr long long O_KC   = 0LL;
constexpr long long O_VC   = 33554432LL;   // + B*T*Hl*D
constexpr long long O_VNT  = 67108864LL;   // + B*T*Hl*D
constexpr long long O_KSUM = 67371008LL;   // + B*T*Hl
constexpr long long O_CNT  = 67895296LL;   // + B*Tb*Hl*D
constexpr long long O_VNB  = 67895808LL;   // + B*Tb
constexpr long long O_PRE  = 67899904LL;   // + B*Tb*Hl

// ws layout (ints): inv[Tc] | cnt[TBc] | maxpos   (~16.6 KB)

__global__ void k_init(int* __restrict__ ws) {
    int i = blockIdx.x * blockDim.x + threadIdx.x;
    if (i < Tc) ws[i] = -1;                  // inv
    else if (i < Tc + TBc) ws[i] = 0;        // cnt
    else if (i == Tc + TBc) ws[i] = -1;      // maxpos
}

__global__ void k_scatter(const int* __restrict__ pos, int* __restrict__ ws) {
    int s = blockIdx.x * blockDim.x + threadIdx.x;
    if (s < Sc) {
        int p = pos[s];
        atomicMax(&ws[p], s);                // last-write-wins on duplicates
        atomicAdd(&ws[Tc + p / BSc], 1);     // per-block token count
        atomicMax(&ws[Tc + TBc], p);         // for prefill_len
    }
}

// One workgroup per (b, tb, h). 256 threads = 8 row-groups x 32 lanes.
// Each 32-lane group moves one 128-float row per iteration (float4/lane).
// Fuses: cache scatter-copy, v_norm_tok scatter, per-block k-sum, v-norm max.
__global__ __launch_bounds__(256) void k_main(
    const float* __restrict__ kc_old, const float* __restrict__ vc_old,
    const float* __restrict__ vnt_old, const float* __restrict__ ksum_old,
    const float* __restrict__ vnb_old, const float* __restrict__ kb,
    const float* __restrict__ vb, const float* __restrict__ vnorm,
    const int* __restrict__ ws, float* __restrict__ out)
{
    const int wg   = blockIdx.x;
    const int h    = wg % HLc;                 // h innermost: consecutive WGs
    const int tb   = (wg / HLc) % TBc;         // cover contiguous 256 KiB
    const int b    = wg / (HLc * TBc);
    const int tid  = threadIdx.x;
    const int g    = tid >> 5;                 // row-group 0..7
    const int lane = tid & 31;                 // d-slice [lane*4, lane*4+4)

    const int* inv = ws;

    float4 ksum = make_float4(0.f, 0.f, 0.f, 0.f);
    float  vmax = -INFINITY;                   // segment_max identity

    float* out_kc  = out + O_KC;
    float* out_vc  = out + O_VC;
    float* out_vnt = out + O_VNT;

    #pragma unroll
    for (int i = 0; i < 8; ++i) {
        const int r = i * 8 + g;               // row within block: 0..63
        const int t = tb * BSc + r;
        const int s = inv[t];
        const long long rowdst = (((long long)b * Tc + t) * HLc + h) * Dc;
        float4 kv, vv;
        if (s >= 0) {
            const long long rowsrc = (((long long)b * Sc + s) * HLc + h) * Dc;
            kv = reinterpret_cast<const float4*>(kb + rowsrc)[lane];
            vv = reinterpret_cast<const float4*>(vb + rowsrc)[lane];
            ksum.x += kv.x; ksum.y += kv.y; ksum.z += kv.z; ksum.w += kv.w;
            if (lane == 0) {
                const float vn = vnorm[((long long)b * Sc + s) * HLc + h];
                vmax = fmaxf(vmax, vn);
                out_vnt[((long long)b * Tc + t) * HLc + h] = vn;
            }
        } else {
            // uncovered slot: carry old cache values through
            kv = reinterpret_cast<const float4*>(kc_old + rowdst)[lane];
            vv = reinterpret_cast<const float4*>(vc_old + rowdst)[lane];
            if (lane == 0) {
                out_vnt[((long long)b * Tc + t) * HLc + h] =
                    vnt_old[((long long)b * Tc + t) * HLc + h];
            }
        }
        reinterpret_cast<float4*>(out_kc + rowdst)[lane] = kv;
        reinterpret_cast<float4*>(out_vc + rowdst)[lane] = vv;
    }

    // Reduce the 8 per-group partial k-sums (each covers all 128 d as
    // 32 lanes x float4) and the 8 partial v-norm maxima.
    __shared__ float lsum[8 * 128];
    __shared__ float lmax[8];
    lsum[g * 128 + lane * 4 + 0] = ksum.x;
    lsum[g * 128 + lane * 4 + 1] = ksum.y;
    lsum[g * 128 + lane * 4 + 2] = ksum.z;
    lsum[g * 128 + lane * 4 + 3] = ksum.w;
    if (lane == 0) lmax[g] = vmax;
    __syncthreads();

    if (tid < Dc) {
        float acc = 0.f;
        #pragma unroll
        for (int gg = 0; gg < 8; ++gg) acc += lsum[gg * 128 + tid];
        const long long o = (((long long)b * TBc + tb) * HLc + h) * Dc + tid;
        out[O_KSUM + o] = ksum_old[o] + acc;
    }
    if (tid == 0) {
        float m = vnb_old[((long long)b * TBc + tb) * HLc + h];
        #pragma unroll
        for (int gg = 0; gg < 8; ++gg) m = fmaxf(m, lmax[gg]);
        out[O_VNB + ((long long)b * TBc + tb) * HLc + h] = m;
    }
}

// Counts (B*Tb) + prefill_len. d_out is read back as float32, so integer
// outputs are written as their float VALUES (exactly representable).
__global__ void k_final(const int* __restrict__ kcnt_old,
                        const int* __restrict__ ws, float* __restrict__ out) {
    int i = blockIdx.x * blockDim.x + threadIdx.x;
    if (i < Bc * TBc) {
        out[O_CNT + i] = (float)(kcnt_old[i] + ws[Tc + (i % TBc)]);
    } else if (i == Bc * TBc) {
        out[O_PRE] = (float)(ws[Tc + TBc] + 1);
    }
}

extern "C" void kernel_launch(void* const* d_in, const int* in_sizes, int n_in,
                              void* d_out, int out_size, void* d_ws, size_t ws_size,
                              hipStream_t stream) {
    const float* kc_old   = (const float*)d_in[0];
    const float* vc_old   = (const float*)d_in[1];
    const float* vnt_old  = (const float*)d_in[2];
    const float* ksum_old = (const float*)d_in[3];
    const int*   kcnt_old = (const int*)d_in[4];
    const float* vnb_old  = (const float*)d_in[5];
    const int*   pos      = (const int*)d_in[6];
    const float* kb       = (const float*)d_in[7];
    const float* vb       = (const float*)d_in[8];
    const float* vnorm    = (const float*)d_in[9];
    int*   ws  = (int*)d_ws;
    float* out = (float*)d_out;

    k_init<<<(Tc + TBc + 1 + 255) / 256, 256, 0, stream>>>(ws);
    k_scatter<<<(Sc + 255) / 256, 256, 0, stream>>>(pos, ws);
    k_main<<<Bc * HLc * TBc, 256, 0, stream>>>(kc_old, vc_old, vnt_old,
                                               ksum_old, vnb_old, kb, vb,
                                               vnorm, ws, out);
    k_final<<<(Bc * TBc + 1 + 255) / 256, 256, 0, stream>>>(kcnt_old, ws, out);
}

// Round 3
// 110.380 us; speedup vs baseline: 1.3072x; 1.3072x over previous
//
#include <hip/hip_runtime.h>
#include <math.h>

// Problem constants (fixed by setup_inputs shapes).
constexpr int Bc  = 8;
constexpr int Tc  = 4096;
constexpr int HLc = 8;
constexpr int Dc  = 128;
constexpr int Sc  = 4096;
constexpr int TBc = 64;   // Tb = T / bs
constexpr int BSc = 64;   // sparse_block_size

// Output offsets (float elements) in concatenated d_out, in return order.
constexpr long long O_KC   = 0LL;
constexpr long long O_VC   = 33554432LL;   // + B*T*Hl*D
constexpr long long O_VNT  = 67108864LL;   // + B*T*Hl*D
constexpr long long O_KSUM = 67371008LL;   // + B*T*Hl
constexpr long long O_CNT  = 67895296LL;   // + B*Tb*Hl*D
constexpr long long O_VNB  = 67895808LL;   // + B*Tb
constexpr long long O_PRE  = 67899904LL;   // + B*Tb*Hl

typedef float f4 __attribute__((ext_vector_type(4)));

// ws layout (ints): inv[Tc] | cnt[TBc] | maxpos

__device__ inline f4 ntload4(const float* p) {
    return __builtin_nontemporal_load(reinterpret_cast<const f4*>(p));
}
__device__ inline void ntstore4(float* p, f4 v) {
    __builtin_nontemporal_store(v, reinterpret_cast<f4*>(p));
}

// Single-WG prep: inverse map, per-block counts, max(pos) — all in LDS
// (no global atomic contention), then one coalesced dump to ws.
__global__ __launch_bounds__(1024) void k_prep(const int* __restrict__ pos,
                                               int* __restrict__ ws) {
    __shared__ int inv_s[Tc];
    __shared__ int cnt_s[TBc];
    __shared__ int maxp_s;
    const int tid = threadIdx.x;
    for (int i = tid; i < Tc; i += 1024) inv_s[i] = -1;
    if (tid < TBc) cnt_s[tid] = 0;
    if (tid == 0) maxp_s = -1;
    __syncthreads();
    int lmax = -1;
    for (int s = tid; s < Sc; s += 1024) {
        const int p = pos[s];
        atomicMax(&inv_s[p], s);          // last-write-wins on duplicates
        atomicAdd(&cnt_s[p / BSc], 1);    // per-block token count
        lmax = max(lmax, p);
    }
    #pragma unroll
    for (int off = 32; off >= 1; off >>= 1)
        lmax = max(lmax, __shfl_xor(lmax, off));
    if ((tid & 63) == 0) atomicMax(&maxp_s, lmax);
    __syncthreads();
    for (int i = tid; i < Tc; i += 1024) ws[i] = inv_s[i];
    if (tid < TBc) ws[Tc + tid] = cnt_s[tid];
    if (tid == 0) ws[Tc + TBc] = maxp_s;
}

// One WG per (b, tb): owns a contiguous 64x(Hl*D) = 256 KB region of each
// cache. Thread -> fixed float4 slot p within the 1024-float row (h = p>>5),
// t-phase q strides the 64 rows. ksum accumulates in registers per (h,d)
// slot -> coalesced float4 write, no cross-thread reduction for the sums.
__global__ __launch_bounds__(1024) void k_main(
    const float* __restrict__ kc_old, const float* __restrict__ vc_old,
    const float* __restrict__ vnt_old, const float* __restrict__ ksum_old,
    const int* __restrict__ kcnt_old, const float* __restrict__ vnb_old,
    const float* __restrict__ kb, const float* __restrict__ vb,
    const float* __restrict__ vnorm, const int* __restrict__ ws,
    float* __restrict__ out)
{
    const int wg  = blockIdx.x;
    const int tb  = wg % TBc;
    const int b   = wg / TBc;
    const int tid = threadIdx.x;
    const int q   = tid >> 8;     // t-phase 0..3
    const int p   = tid & 255;    // float4 slot within row

    __shared__ int   inv_l[BSc];
    __shared__ f4    red4[1024];
    __shared__ float vn_l[BSc * HLc];

    if (tid < BSc) inv_l[tid] = ws[tb * BSc + tid];
    __syncthreads();

    const long long ROW     = (long long)HLc * Dc;              // 1024
    const long long dstBase = ((long long)(b * Tc + tb * BSc)) * ROW;
    const long long srcBase = ((long long)b * Sc) * ROW;

    f4 ksum = (f4){0.f, 0.f, 0.f, 0.f};
    #pragma unroll
    for (int i = 0; i < 16; ++i) {
        const int r = i * 4 + q;                  // row in block 0..63
        const int s = inv_l[r];
        const long long dst = dstBase + (long long)r * ROW + p * 4;
        f4 kv, vv;
        if (s >= 0) {
            const long long src = srcBase + (long long)s * ROW + p * 4;
            kv = ntload4(kb + src);
            vv = ntload4(vb + src);
            ksum += kv;
        } else {
            kv = ntload4(kc_old + dst);
            vv = ntload4(vc_old + dst);
        }
        ntstore4(out + O_KC + dst, kv);
        ntstore4(out + O_VC + dst, vv);
    }

    // v_norm_tok: 512 contiguous floats per WG, fully coalesced; stash
    // incoming values in LDS for the per-h max.
    if (tid < BSc * HLc) {
        const int tl = tid >> 3, h = tid & 7;
        const int s  = inv_l[tl];
        const long long di = ((long long)(b * Tc + tb * BSc + tl)) * HLc + h;
        float vn, vm;
        if (s >= 0) {
            vn = vnorm[(((long long)b * Sc) + s) * HLc + h];
            vm = vn;
        } else {
            vn = vnt_old[di];
            vm = -INFINITY;
        }
        out[O_VNT + di] = vn;
        vn_l[tid] = vm;
    }
    red4[tid] = ksum;
    __syncthreads();

    // k_sum_blk: reduce 4 t-phase partials per slot, add old, write float4.
    if (q == 0) {
        f4 a = red4[p], c = red4[256 + p], d = red4[512 + p],
           e = red4[768 + p];
        const long long o = ((long long)(b * TBc + tb)) * ROW + p * 4;
        f4 old = *reinterpret_cast<const f4*>(ksum_old + o);
        f4 tot = old + a + c + d + e;
        ntstore4(out + O_KSUM + o, tot);
    }

    // v_norm_blk: per-h running max.
    if (tid < HLc) {
        float m = vnb_old[((long long)(b * TBc + tb)) * HLc + tid];
        #pragma unroll
        for (int t = 0; t < BSc; ++t) m = fmaxf(m, vn_l[t * HLc + tid]);
        out[O_VNB + ((long long)(b * TBc + tb)) * HLc + tid] = m;
    }

    // counts + prefill_len (d_out read back as float32: write values).
    if (tid == 0) {
        out[O_CNT + b * TBc + tb] =
            (float)(kcnt_old[b * TBc + tb] + ws[Tc + tb]);
        if (wg == 0) out[O_PRE] = (float)(ws[Tc + TBc] + 1);
    }
}

extern "C" void kernel_launch(void* const* d_in, const int* in_sizes, int n_in,
                              void* d_out, int out_size, void* d_ws, size_t ws_size,
                              hipStream_t stream) {
    const float* kc_old   = (const float*)d_in[0];
    const float* vc_old   = (const float*)d_in[1];
    const float* vnt_old  = (const float*)d_in[2];
    const float* ksum_old = (const float*)d_in[3];
    const int*   kcnt_old = (const int*)d_in[4];
    const float* vnb_old  = (const float*)d_in[5];
    const int*   pos      = (const int*)d_in[6];
    const float* kb       = (const float*)d_in[7];
    const float* vb       = (const float*)d_in[8];
    const float* vnorm    = (const float*)d_in[9];
    int*   ws  = (int*)d_ws;
    float* out = (float*)d_out;

    k_prep<<<1, 1024, 0, stream>>>(pos, ws);
    k_main<<<Bc * TBc, 1024, 0, stream>>>(kc_old, vc_old, vnt_old, ksum_old,
                                          kcnt_old, vnb_old, kb, vb, vnorm,
                                          ws, out);
}

// Round 4
// 106.333 us; speedup vs baseline: 1.3570x; 1.0381x over previous
//
#include <hip/hip_runtime.h>
#include <math.h>

// Problem constants (fixed by setup_inputs shapes).
constexpr int Bc  = 8;
constexpr int Tc  = 4096;
constexpr int HLc = 8;
constexpr int Dc  = 128;
constexpr int Sc  = 4096;
constexpr int TBc = 64;   // Tb = T / bs
constexpr int BSc = 64;   // sparse_block_size

// Output offsets (float elements) in concatenated d_out, in return order.
constexpr long long O_KC   = 0LL;
constexpr long long O_VC   = 33554432LL;   // + B*T*Hl*D
constexpr long long O_VNT  = 67108864LL;   // + B*T*Hl*D
constexpr long long O_KSUM = 67371008LL;   // + B*T*Hl
constexpr long long O_CNT  = 67895296LL;   // + B*Tb*Hl*D
constexpr long long O_VNB  = 67895808LL;   // + B*Tb
constexpr long long O_PRE  = 67899904LL;   // + B*Tb*Hl

typedef float f4 __attribute__((ext_vector_type(4)));

__device__ inline f4 ntload4(const float* p) {
    return __builtin_nontemporal_load(reinterpret_cast<const f4*>(p));
}
__device__ inline void ntstore4(float* p, f4 v) {
    __builtin_nontemporal_store(v, reinterpret_cast<f4*>(p));
}

// Single fused kernel. One WG per (b, tb): owns a contiguous 64x(Hl*D)
// = 256 KB region of each cache. Prep (inverse map / count / maxpos) is
// computed per-WG from pos[] (16 KB, L2-resident after first WG) — no
// separate kernel, no global scratch.
__global__ __launch_bounds__(1024) void k_main(
    const float* __restrict__ kc_old, const float* __restrict__ vc_old,
    const float* __restrict__ vnt_old, const float* __restrict__ ksum_old,
    const int* __restrict__ kcnt_old, const float* __restrict__ vnb_old,
    const float* __restrict__ kb, const float* __restrict__ vb,
    const float* __restrict__ vnorm, const int* __restrict__ pos,
    float* __restrict__ out)
{
    const int wg  = blockIdx.x;
    const int tb  = wg % TBc;
    const int b   = wg / TBc;
    const int tid = threadIdx.x;
    const int q   = tid >> 8;     // t-phase 0..3
    const int p   = tid & 255;    // float4 slot within row

    __shared__ int   inv_l[BSc];
    __shared__ int   cnt_l;
    __shared__ int   maxp_l;
    __shared__ f4    red4[1024];
    __shared__ float vn_l[BSc * HLc];

    if (tid < BSc) inv_l[tid] = -1;
    if (tid == 0) { cnt_l = 0; maxp_l = -1; }
    __syncthreads();

    // Per-WG prep scan over pos[] (uniform across WGs -> cache-resident).
    {
        const int base = tb * BSc;
        int lmax = -1;
        #pragma unroll
        for (int j = 0; j < Sc / 1024; ++j) {
            const int s  = tid + j * 1024;
            const int pp = pos[s];
            lmax = max(lmax, pp);
            if (pp >= base && pp < base + BSc) {
                atomicMax(&inv_l[pp - base], s);   // last-write-wins on dups
                atomicAdd(&cnt_l, 1);
            }
        }
        if (wg == 0) {   // only WG 0 needs max(pos) for prefill_len
            #pragma unroll
            for (int off = 32; off >= 1; off >>= 1)
                lmax = max(lmax, __shfl_xor(lmax, off));
            if ((tid & 63) == 0) atomicMax(&maxp_l, lmax);
        }
    }
    __syncthreads();

    const long long ROW     = (long long)HLc * Dc;              // 1024
    const long long dstBase = ((long long)(b * Tc + tb * BSc)) * ROW;
    const long long srcBase = ((long long)b * Sc) * ROW;

    f4 ksum = (f4){0.f, 0.f, 0.f, 0.f};
    #pragma unroll
    for (int i = 0; i < 16; ++i) {
        const int r = i * 4 + q;                  // row in block 0..63
        const int s = inv_l[r];
        const long long dst = dstBase + (long long)r * ROW + p * 4;
        f4 kv, vv;
        if (s >= 0) {
            const long long src = srcBase + (long long)s * ROW + p * 4;
            kv = ntload4(kb + src);
            vv = ntload4(vb + src);
            ksum += kv;
        } else {
            kv = ntload4(kc_old + dst);
            vv = ntload4(vc_old + dst);
        }
        ntstore4(out + O_KC + dst, kv);
        ntstore4(out + O_VC + dst, vv);
    }

    // v_norm_tok: 512 contiguous floats per WG, fully coalesced; stash
    // incoming values in LDS for the per-h max.
    if (tid < BSc * HLc) {
        const int tl = tid >> 3, h = tid & 7;
        const int s  = inv_l[tl];
        const long long di = ((long long)(b * Tc + tb * BSc + tl)) * HLc + h;
        float vn, vm;
        if (s >= 0) {
            vn = vnorm[(((long long)b * Sc) + s) * HLc + h];
            vm = vn;
        } else {
            vn = vnt_old[di];
            vm = -INFINITY;
        }
        out[O_VNT + di] = vn;
        vn_l[tid] = vm;
    }
    red4[tid] = ksum;
    __syncthreads();

    // k_sum_blk: reduce 4 t-phase partials per slot, add old, write float4.
    if (q == 0) {
        f4 a = red4[p], c = red4[256 + p], d = red4[512 + p],
           e = red4[768 + p];
        const long long o = ((long long)(b * TBc + tb)) * ROW + p * 4;
        f4 old = *reinterpret_cast<const f4*>(ksum_old + o);
        f4 tot = old + a + c + d + e;
        ntstore4(out + O_KSUM + o, tot);
    }

    // v_norm_blk: per-h running max.
    if (tid < HLc) {
        float m = vnb_old[((long long)(b * TBc + tb)) * HLc + tid];
        #pragma unroll
        for (int t = 0; t < BSc; ++t) m = fmaxf(m, vn_l[t * HLc + tid]);
        out[O_VNB + ((long long)(b * TBc + tb)) * HLc + tid] = m;
    }

    // counts + prefill_len (d_out read back as float32: write values).
    if (tid == 0) {
        out[O_CNT + b * TBc + tb] = (float)(kcnt_old[b * TBc + tb] + cnt_l);
        if (wg == 0) out[O_PRE] = (float)(maxp_l + 1);
    }
}

extern "C" void kernel_launch(void* const* d_in, const int* in_sizes, int n_in,
                              void* d_out, int out_size, void* d_ws, size_t ws_size,
                              hipStream_t stream) {
    const float* kc_old   = (const float*)d_in[0];
    const float* vc_old   = (const float*)d_in[1];
    const float* vnt_old  = (const float*)d_in[2];
    const float* ksum_old = (const float*)d_in[3];
    const int*   kcnt_old = (const int*)d_in[4];
    const float* vnb_old  = (const float*)d_in[5];
    const int*   pos      = (const int*)d_in[6];
    const float* kb       = (const float*)d_in[7];
    const float* vb       = (const float*)d_in[8];
    const float* vnorm    = (const float*)d_in[9];
    float* out = (float*)d_out;

    k_main<<<Bc * TBc, 1024, 0, stream>>>(kc_old, vc_old, vnt_old, ksum_old,
                                          kcnt_old, vnb_old, kb, vb, vnorm,
                                          pos, out);
}